// Round 1
// baseline (358.588 us; speedup 1.0000x reference)
//
#include <hip/hip_runtime.h>
#include <math.h>

#define ROWS 65536
#define COLS 1000
#define STRIDE 1001
#define K1_BLOCKS 2048
#define WAVES_PER_BLOCK 4
#define EPSV 1e-6f

// One wave (64 lanes) per row. Row = 1000 logits + 1 "extra".
// Single pass over HBM: row lives in 16 regs/lane.
__global__ __launch_bounds__(256) void row_loss_kernel(
    const float* __restrict__ in, float* __restrict__ partial) {
    const int lane  = threadIdx.x & 63;
    const int wave  = threadIdx.x >> 6;
    const int gwave = blockIdx.x * WAVES_PER_BLOCK + wave;
    const int nwaves = gridDim.x * WAVES_PER_BLOCK;

    float wsum = 0.0f;
    for (int row = gwave; row < ROWS; row += nwaves) {
        const float* rp = in + (size_t)row * STRIDE;

        // Load row: lane handles columns lane + 64*k, k = 0..15 (1024 >= 1000)
        float l[16];
        #pragma unroll
        for (int k = 0; k < 16; ++k) {
            int c = lane + 64 * k;
            l[k] = (c < COLS) ? rp[c] : -INFINITY;
        }
        float extra = rp[COLS];  // wave-uniform address -> broadcast

        // Row max (registers then 6-step butterfly)
        float m = l[0];
        #pragma unroll
        for (int k = 1; k < 16; ++k) m = fmaxf(m, l[k]);
        #pragma unroll
        for (int off = 32; off > 0; off >>= 1) m = fmaxf(m, __shfl_xor(m, off));

        // Sum of exp(l - m), keep numerators in regs
        float e[16];
        float se = 0.0f;
        #pragma unroll
        for (int k = 0; k < 16; ++k) {
            int c = lane + 64 * k;
            float v = (c < COLS) ? __expf(l[k] - m) : 0.0f;
            e[k] = v;
            se += v;
        }
        #pragma unroll
        for (int off = 32; off > 0; off >>= 1) se += __shfl_xor(se, off);
        float rdenom = 1.0f / se;  // wave-uniform, once per row

        // sum_c prob_c * log(sigmoid(extra - l_c))
        float t = 0.0f;
        #pragma unroll
        for (int k = 0; k < 16; ++k) {
            int c = lane + 64 * k;
            if (c < COLS) {
                float p = e[k] * rdenom;
                float x = extra - l[k];
                float s = __builtin_amdgcn_rcpf(1.0f + __expf(-x));  // sigmoid
                if (s == 0.0f) s = EPSV;  // reference's pc==0 guard
                t += p * __logf(s);
            }
        }
        #pragma unroll
        for (int off = 32; off > 0; off >>= 1) t += __shfl_xor(t, off);
        wsum += t;  // identical across lanes after full butterfly
    }

    __shared__ float sdata[WAVES_PER_BLOCK];
    if (lane == 0) sdata[wave] = wsum;
    __syncthreads();
    if (threadIdx.x == 0) {
        float b = 0.0f;
        #pragma unroll
        for (int w = 0; w < WAVES_PER_BLOCK; ++w) b += sdata[w];
        partial[blockIdx.x] = b;
    }
}

__global__ __launch_bounds__(256) void final_reduce(
    const float* __restrict__ partial, float* __restrict__ out) {
    float s = 0.0f;
    for (int i = threadIdx.x; i < K1_BLOCKS; i += 256) s += partial[i];
    #pragma unroll
    for (int off = 32; off > 0; off >>= 1) s += __shfl_xor(s, off);
    __shared__ float sdata[4];
    const int lane = threadIdx.x & 63, wave = threadIdx.x >> 6;
    if (lane == 0) sdata[wave] = s;
    __syncthreads();
    if (threadIdx.x == 0) {
        float tot = sdata[0] + sdata[1] + sdata[2] + sdata[3];
        out[0] = -tot / (float)ROWS;
    }
}

extern "C" void kernel_launch(void* const* d_in, const int* in_sizes, int n_in,
                              void* d_out, int out_size, void* d_ws, size_t ws_size,
                              hipStream_t stream) {
    const float* in = (const float*)d_in[0];   // (65536, 1001) fp32
    // d_in[1] (target) is unused by the reference computation.
    float* partial = (float*)d_ws;             // K1_BLOCKS floats
    row_loss_kernel<<<K1_BLOCKS, 256, 0, stream>>>(in, partial);
    final_reduce<<<1, 256, 0, stream>>>(partial, (float*)d_out);
}